// Round 3
// baseline (13749.352 us; speedup 1.0000x reference)
//
#include <hip/hip_runtime.h>
#include <hip/hip_bf16.h>

#define N_NODES 40962
#define N_EDGES 327680
#define NDIM 256
#define EDIM 64
#define HDIM 512
#define NLAYERS 16

using bf16_t = __bf16;
using bf16x4 = __bf16 __attribute__((ext_vector_type(4)));
using bf16x8 = __bf16 __attribute__((ext_vector_type(8)));
using f32x4  = float __attribute__((ext_vector_type(4)));

// XOR swizzle: element address within a row-major LDS tile; stride in elements
// must be a multiple of 64 (128 B) for bijectivity. Toggles byte bits 4-6.
#define SWE(r, eo) ((r) * 576 + ((eo) ^ (((r) & 7) << 3)))   // edge tile, stride 576
#define SWN(r, eo) ((r) * 512 + ((eo) ^ (((r) & 7) << 3)))   // node tile, stride 512

__device__ __forceinline__ int clamp_idx(int v) {
    return v < 0 ? 0 : (v >= N_NODES ? N_NODES - 1 : v);
}

__device__ __forceinline__ bf16x8 zero8() {
    bf16x8 z;
#pragma unroll
    for (int j = 0; j < 8; ++j) z[j] = (bf16_t)0.f;
    return z;
}

// ---------------------------------------------------------------------------
// Weight repack: W[l][k][n] (fp32 KxN) -> bf16 MFMA B-fragment order.
// mode 1: edge-W1 K remap for A-order [x_src|x_dst|e]: orig_k = k<512? k+64 : k-512
// ---------------------------------------------------------------------------
__global__ void repack_w(const float* __restrict__ src, bf16_t* __restrict__ dst,
                         int K, int N, int tilesPer, int mode) {
    int idx = blockIdx.x * 256 + threadIdx.x;
    int lane = idx & 63;
    int t = idx >> 6;
    int l = t / tilesPer;
    int tile = t % tilesPer;
    if (l >= NLAYERS) return;
    int ntN = N >> 4;
    int k0 = (tile / ntN) << 5;
    int n0 = (tile % ntN) << 4;
    int k = k0 + (lane >> 4) * 8;          // chunk of 8 consecutive k
    int n = n0 + (lane & 15);
    if (mode == 1) k = (k < 512) ? k + 64 : k - 512;   // 8-chunks never cross 512
    const float* s = src + (size_t)l * K * N + (size_t)k * N + n;
    bf16x8 v;
#pragma unroll
    for (int j = 0; j < 8; ++j) v[j] = (bf16_t)s[(size_t)j * N];
    *(bf16x8*)(dst + (size_t)idx * 8) = v;
}

__global__ void init_e2(const float* __restrict__ ef, bf16_t* __restrict__ es, int n8) {
    const size_t per = (size_t)N_EDGES * EDIM;
    for (int i = blockIdx.x * 256 + threadIdx.x; i < n8; i += gridDim.x * 256) {
        float4 a = *(const float4*)(ef + (size_t)i * 8);
        float4 b = *(const float4*)(ef + (size_t)i * 8 + 4);
        bf16x8 v;
        v[0] = (bf16_t)a.x; v[1] = (bf16_t)a.y; v[2] = (bf16_t)a.z; v[3] = (bf16_t)a.w;
        v[4] = (bf16_t)b.x; v[5] = (bf16_t)b.y; v[6] = (bf16_t)b.z; v[7] = (bf16_t)b.w;
        *(bf16x8*)(es + (size_t)i * 8) = v;
        *(bf16x8*)(es + per + (size_t)i * 8) = v;
    }
}

__global__ void f32_to_bf16(const float* __restrict__ src, bf16_t* __restrict__ dst, int n8) {
    for (int i = blockIdx.x * 256 + threadIdx.x; i < n8; i += gridDim.x * 256) {
        float4 a = *(const float4*)(src + (size_t)i * 8);
        float4 b = *(const float4*)(src + (size_t)i * 8 + 4);
        bf16x8 v;
        v[0] = (bf16_t)a.x; v[1] = (bf16_t)a.y; v[2] = (bf16_t)a.z; v[3] = (bf16_t)a.w;
        v[4] = (bf16_t)b.x; v[5] = (bf16_t)b.y; v[6] = (bf16_t)b.z; v[7] = (bf16_t)b.w;
        *(bf16x8*)(dst + (size_t)i * 8) = v;
    }
}

__global__ void zero_f32(float* __restrict__ p, int n4) {
    float4 z; z.x = z.y = z.z = z.w = 0.f;
    for (int i = blockIdx.x * 256 + threadIdx.x; i < n4; i += gridDim.x * 256)
        *(float4*)(p + (size_t)i * 4) = z;
}

// ---------------------------------------------------------------------------
// One-time CSR build over dst (edge_index constant across layers & batches).
// ---------------------------------------------------------------------------
__global__ void hist_k(const int* __restrict__ eidx, int* __restrict__ deg) {
    int e = blockIdx.x * 256 + threadIdx.x;
    if (e < N_EDGES) atomicAdd(&deg[clamp_idx(eidx[N_EDGES + e])], 1);
}

__global__ void scan_k(const int* __restrict__ deg, int* __restrict__ off,
                       int* __restrict__ cur) {
    __shared__ int part[1024];
    const int t = threadIdx.x;
    const int C = (N_NODES + 1023) / 1024;   // 41
    int lo = t * C, hi = min((t + 1) * C, N_NODES);
    int s = 0;
    for (int i = lo; i < hi; ++i) s += deg[i];
    part[t] = s;
    __syncthreads();
    for (int d = 1; d < 1024; d <<= 1) {
        int v = (t >= d) ? part[t - d] : 0;
        __syncthreads();
        part[t] += v;
        __syncthreads();
    }
    int base = (t == 0) ? 0 : part[t - 1];
    for (int i = lo; i < hi; ++i) {
        off[i] = base;
        cur[i] = base;
        base += deg[i];
    }
    if (t == 1023) off[N_NODES] = part[1023];
}

__global__ void fill_k(const int* __restrict__ eidx, int* __restrict__ cur,
                       int* __restrict__ csr) {
    int e = blockIdx.x * 256 + threadIdx.x;
    if (e < N_EDGES) {
        int d = clamp_idx(eidx[N_EDGES + e]);
        int pos = atomicAdd(&cur[d], 1);
        csr[pos] = e;
    }
}

// ---------------------------------------------------------------------------
// Edge kernel: 1024 threads (16 waves), 64-edge tile x BOTH batches (M=128).
//   A rows (stride 576, XOR-swizzled): [x_src(0:256) | x_dst(256:512) | e(512:576)]
//   MLP1: wave wv -> cols [wv*32,+32); H overwrites A cols [0,512); e survives.
//   MLP2: wave (strip=wv>>1, nh=wv&1) -> rows [strip*16,+16), cols [nh*32,+32)
// ---------------------------------------------------------------------------
__global__ __launch_bounds__(1024, 4)
void edge_kernel(const bf16_t* __restrict__ x16, bf16_t* __restrict__ es,
                 const int* __restrict__ eidx,
                 const bf16_t* __restrict__ w1p, const float* __restrict__ b1,
                 const bf16_t* __restrict__ w2p, const float* __restrict__ b2,
                 const float* __restrict__ gw, const float* __restrict__ bw) {
    __shared__ bf16_t smem[128 * 576];   // 147456 B
    __shared__ float red[128 * 4];
    __shared__ int sSrc[64], sDst[64];

    const int e0  = blockIdx.x * 64;
    const int tid = threadIdx.x;
    const size_t PER_E = (size_t)N_EDGES * EDIM;
    const size_t PER_X = (size_t)N_NODES * NDIM;

    if (tid < 64) {
        sSrc[tid] = clamp_idx(eidx[e0 + tid]);
        sDst[tid] = clamp_idx(eidx[N_EDGES + e0 + tid]);
    }
    __syncthreads();

    {   // e: 128 rows x 8 chunks -> one bf16x8 per thread
        int r = tid >> 3, c = (tid & 7) << 3;
        bf16x8 v = *(const bf16x8*)(es + (size_t)(r >> 6) * PER_E
                                       + (size_t)(e0 + (r & 63)) * EDIM + c);
        *(bf16x8*)&smem[SWE(r, 512 + c)] = v;
    }
#pragma unroll
    for (int k = 0; k < 4; ++k) {   // x_src: 128 rows x 32 chunks
        int i = tid + k * 1024;
        int r = i >> 5, c = (i & 31) << 3;
        bf16x8 v = *(const bf16x8*)(x16 + (size_t)(r >> 6) * PER_X
                                        + (size_t)sSrc[r & 63] * NDIM + c);
        *(bf16x8*)&smem[SWE(r, c)] = v;
    }
#pragma unroll
    for (int k = 0; k < 4; ++k) {   // x_dst
        int i = tid + k * 1024;
        int r = i >> 5, c = (i & 31) << 3;
        bf16x8 v = *(const bf16x8*)(x16 + (size_t)(r >> 6) * PER_X
                                        + (size_t)sDst[r & 63] * NDIM + c);
        *(bf16x8*)&smem[SWE(r, 256 + c)] = v;
    }
    __syncthreads();

    const int wv = tid >> 6, lane = tid & 63;
    const int m16 = lane & 15, quad = lane >> 4;

    // ---- MLP1: M=128, K=576, N=512. wave wv -> cols [wv*32,+32)
    float bias1[2];
    bias1[0] = b1[wv * 32 + m16];
    bias1[1] = b1[wv * 32 + 16 + m16];

    f32x4 acc1[8][2];
#pragma unroll
    for (int mt = 0; mt < 8; ++mt)
#pragma unroll
        for (int nt = 0; nt < 2; ++nt)
            acc1[mt][nt] = (f32x4){bias1[nt], bias1[nt], bias1[nt], bias1[nt]};

    const bf16x8* W1 = (const bf16x8*)w1p;
#pragma unroll 2
    for (int kc = 0; kc < 18; ++kc) {
        bf16x8 bfr[2];
#pragma unroll
        for (int nt = 0; nt < 2; ++nt)
            bfr[nt] = W1[(size_t)(kc * 32 + wv * 2 + nt) * 64 + lane];
#pragma unroll
        for (int g = 0; g < 2; ++g) {   // row halves to cap af register pressure
            bf16x8 af[4];
#pragma unroll
            for (int j = 0; j < 4; ++j) {
                int R = g * 64 + j * 16 + m16;
                af[j] = *(const bf16x8*)&smem[SWE(R, kc * 32 + quad * 8)];
            }
#pragma unroll
            for (int j = 0; j < 4; ++j)
#pragma unroll
                for (int nt = 0; nt < 2; ++nt)
                    acc1[g * 4 + j][nt] = __builtin_amdgcn_mfma_f32_16x16x32_bf16(
                        af[j], bfr[nt], acc1[g * 4 + j][nt], 0, 0, 0);
        }
    }
    __syncthreads();   // all waves done reading A before H overwrites cols [0,512)

#pragma unroll
    for (int mt = 0; mt < 8; ++mt)
#pragma unroll
        for (int nt = 0; nt < 2; ++nt)
#pragma unroll
            for (int r = 0; r < 4; ++r) {
                int row = mt * 16 + quad * 4 + r;
                int col = wv * 32 + nt * 16 + m16;
                float v = acc1[mt][nt][r];
                v = v / (1.f + __expf(-v));
                smem[SWE(row, col)] = (bf16_t)v;
            }
    __syncthreads();

    // ---- MLP2: M=128, K=512, N=64. wave (strip, nh)
    const int strip = wv >> 1, nh = wv & 1;
    float bias2[2], g2[2], bl2[2];
#pragma unroll
    for (int nt = 0; nt < 2; ++nt) {
        int c = nh * 32 + nt * 16 + m16;
        bias2[nt] = b2[c];
        g2[nt]    = gw[c];
        bl2[nt]   = bw[c];
    }
    f32x4 acc2[2];
#pragma unroll
    for (int nt = 0; nt < 2; ++nt)
        acc2[nt] = (f32x4){bias2[nt], bias2[nt], bias2[nt], bias2[nt]};
    const bf16x8* W2 = (const bf16x8*)w2p;
#pragma unroll 2
    for (int kc = 0; kc < 16; ++kc) {
        int R = strip * 16 + m16;
        bf16x8 a2 = *(const bf16x8*)&smem[SWE(R, kc * 32 + quad * 8)];
#pragma unroll
        for (int nt = 0; nt < 2; ++nt) {
            bf16x8 b2f = W2[(size_t)(kc * 4 + nh * 2 + nt) * 64 + lane];
            acc2[nt] = __builtin_amdgcn_mfma_f32_16x16x32_bf16(a2, b2f, acc2[nt], 0, 0, 0);
        }
    }

    // LN(64) partials
    float v[4][2];
#pragma unroll
    for (int r = 0; r < 4; ++r) {
        float s1 = 0.f, s2 = 0.f;
#pragma unroll
        for (int nt = 0; nt < 2; ++nt) {
            v[r][nt] = acc2[nt][r];
            s1 += v[r][nt]; s2 += v[r][nt] * v[r][nt];
        }
#pragma unroll
        for (int o = 1; o < 16; o <<= 1) {
            s1 += __shfl_xor(s1, o);
            s2 += __shfl_xor(s2, o);
        }
        if (m16 == 0) {
            int row = strip * 16 + quad * 4 + r;
            red[row * 4 + nh * 2 + 0] = s1;
            red[row * 4 + nh * 2 + 1] = s2;
        }
    }
    __syncthreads();

    // LN final; e residual read from LDS (cols 512..576 survived H-alias)
    float en[4][2];
#pragma unroll
    for (int r = 0; r < 4; ++r) {
        int row = strip * 16 + quad * 4 + r;
        float s1 = red[row * 4 + 0] + red[row * 4 + 2];
        float s2 = red[row * 4 + 1] + red[row * 4 + 3];
        float mean = s1 * (1.f / 64.f);
        float var  = s2 * (1.f / 64.f) - mean * mean;
        float rstd = rsqrtf(fmaxf(var, 0.f) + 1e-5f);
#pragma unroll
        for (int nt = 0; nt < 2; ++nt) {
            int c = nh * 32 + nt * 16 + m16;
            float ln = (v[r][nt] - mean) * rstd * g2[nt] + bl2[nt];
            en[r][nt] = (float)smem[SWE(row, 512 + c)] + ln;
        }
    }
    __syncthreads();   // every thread holds its e-residuals; safe to clobber

#pragma unroll
    for (int r = 0; r < 4; ++r) {
        int row = strip * 16 + quad * 4 + r;
#pragma unroll
        for (int nt = 0; nt < 2; ++nt) {
            int c = nh * 32 + nt * 16 + m16;
            smem[row * 64 + c] = (bf16_t)en[r][nt];   // e_out staging, unswizzled
        }
    }
    __syncthreads();
    {   // coalesced e write: 1024 x 16B
        int r = tid >> 3, c = (tid & 7) << 3;
        *(bf16x8*)(es + (size_t)(r >> 6) * PER_E + (size_t)(e0 + (r & 63)) * EDIM + c) =
            *(bf16x8*)&smem[r * 64 + c];
    }
}

// ---------------------------------------------------------------------------
// Node kernel: 1024 threads (16 waves), 64-node tile x BOTH batches (M=128).
//   A (stride 512, XOR-swizzled): [x(0:256) | agg(256:320)]; H overwrites [0:512).
//   CSR gather 4-wide unrolled to break load dependence chain.
// ---------------------------------------------------------------------------
__global__ __launch_bounds__(1024, 4)
void node_kernel(float* __restrict__ xs, bf16_t* __restrict__ x16,
                 const bf16_t* __restrict__ es,
                 const int* __restrict__ off, const int* __restrict__ csr,
                 const bf16_t* __restrict__ w1p, const float* __restrict__ b1,
                 const bf16_t* __restrict__ w2p, const float* __restrict__ b2,
                 const float* __restrict__ gw, const float* __restrict__ bw) {
    __shared__ bf16_t smem[128 * 512];   // 131072 B
    __shared__ float red[128 * 4];

    const int n0  = blockIdx.x * 64;
    const int tid = threadIdx.x;
    const size_t PER_E = (size_t)N_EDGES * EDIM;
    const size_t PER_X = (size_t)N_NODES * NDIM;

    const int wv = tid >> 6, lane = tid & 63;
    const int m16 = lane & 15, quad = lane >> 4;

#pragma unroll
    for (int k = 0; k < 4; ++k) {   // x: 128 rows x 32 chunks
        int i = tid + k * 1024;
        int r = i >> 5, c = (i & 31) << 3;
        int node = n0 + (r & 63);
        bf16x8 v = (node < N_NODES)
            ? *(const bf16x8*)(x16 + (size_t)(r >> 6) * PER_X + (size_t)node * NDIM + c)
            : zero8();
        *(bf16x8*)&smem[SWN(r, c)] = v;
    }
    // agg via CSR: wave wv -> rows [wv*8,+8); lane = column; 4-wide unroll
#pragma unroll 1
    for (int rr = 0; rr < 8; ++rr) {
        int row = wv * 8 + rr;
        int node = n0 + (row & 63);
        float acc = 0.f;
        if (node < N_NODES) {
            const bf16_t* ebb = es + (size_t)(row >> 6) * PER_E;
            int js = off[node], je = off[node + 1];
            int j = js;
            for (; j + 4 <= je; j += 4) {
                int i0 = csr[j], i1 = csr[j + 1], i2 = csr[j + 2], i3 = csr[j + 3];
                float a0 = (float)ebb[(size_t)i0 * EDIM + lane];
                float a1 = (float)ebb[(size_t)i1 * EDIM + lane];
                float a2 = (float)ebb[(size_t)i2 * EDIM + lane];
                float a3 = (float)ebb[(size_t)i3 * EDIM + lane];
                acc += (a0 + a1) + (a2 + a3);
            }
            for (; j < je; ++j)
                acc += (float)ebb[(size_t)csr[j] * EDIM + lane];
        }
        smem[SWN(row, 256 + lane)] = (bf16_t)acc;
    }
    __syncthreads();

    // ---- MLP1: M=128, K=320, N=512
    float bias1[2];
    bias1[0] = b1[wv * 32 + m16];
    bias1[1] = b1[wv * 32 + 16 + m16];

    f32x4 acc1[8][2];
#pragma unroll
    for (int mt = 0; mt < 8; ++mt)
#pragma unroll
        for (int nt = 0; nt < 2; ++nt)
            acc1[mt][nt] = (f32x4){bias1[nt], bias1[nt], bias1[nt], bias1[nt]};

    const bf16x8* W1 = (const bf16x8*)w1p;
#pragma unroll 2
    for (int kc = 0; kc < 10; ++kc) {
        bf16x8 bfr[2];
#pragma unroll
        for (int nt = 0; nt < 2; ++nt)
            bfr[nt] = W1[(size_t)(kc * 32 + wv * 2 + nt) * 64 + lane];
#pragma unroll
        for (int g = 0; g < 2; ++g) {
            bf16x8 af[4];
#pragma unroll
            for (int j = 0; j < 4; ++j) {
                int R = g * 64 + j * 16 + m16;
                af[j] = *(const bf16x8*)&smem[SWN(R, kc * 32 + quad * 8)];
            }
#pragma unroll
            for (int j = 0; j < 4; ++j)
#pragma unroll
                for (int nt = 0; nt < 2; ++nt)
                    acc1[g * 4 + j][nt] = __builtin_amdgcn_mfma_f32_16x16x32_bf16(
                        af[j], bfr[nt], acc1[g * 4 + j][nt], 0, 0, 0);
        }
    }
    __syncthreads();

#pragma unroll
    for (int mt = 0; mt < 8; ++mt)
#pragma unroll
        for (int nt = 0; nt < 2; ++nt)
#pragma unroll
            for (int r = 0; r < 4; ++r) {
                int row = mt * 16 + quad * 4 + r;
                int col = wv * 32 + nt * 16 + m16;
                float v = acc1[mt][nt][r];
                v = v / (1.f + __expf(-v));
                smem[SWN(row, col)] = (bf16_t)v;
            }
    __syncthreads();

    // ---- MLP2: M=128, K=512, N=256. wave (strip, nh) -> rows 16, cols [nh*128,+128)
    const int strip = wv >> 1, nh = wv & 1;
    float bias2[8], g8[8], bl8[8];
#pragma unroll
    for (int nt = 0; nt < 8; ++nt) {
        int c = nh * 128 + nt * 16 + m16;
        bias2[nt] = b2[c];
        g8[nt]    = gw[c];
        bl8[nt]   = bw[c];
    }
    f32x4 acc2[8];
#pragma unroll
    for (int nt = 0; nt < 8; ++nt)
        acc2[nt] = (f32x4){bias2[nt], bias2[nt], bias2[nt], bias2[nt]};
    const bf16x8* W2 = (const bf16x8*)w2p;
#pragma unroll 2
    for (int kc = 0; kc < 16; ++kc) {
        int R = strip * 16 + m16;
        bf16x8 a2 = *(const bf16x8*)&smem[SWN(R, kc * 32 + quad * 8)];
#pragma unroll
        for (int nt = 0; nt < 8; ++nt) {
            bf16x8 b2f = W2[(size_t)(kc * 16 + nh * 8 + nt) * 64 + lane];
            acc2[nt] = __builtin_amdgcn_mfma_f32_16x16x32_bf16(a2, b2f, acc2[nt], 0, 0, 0);
        }
    }

    float v[4][8];
#pragma unroll
    for (int r = 0; r < 4; ++r) {
        float s1 = 0.f, s2 = 0.f;
#pragma unroll
        for (int nt = 0; nt < 8; ++nt) {
            v[r][nt] = acc2[nt][r];
            s1 += v[r][nt]; s2 += v[r][nt] * v[r][nt];
        }
#pragma unroll
        for (int o = 1; o < 16; o <<= 1) {
            s1 += __shfl_xor(s1, o);
            s2 += __shfl_xor(s2, o);
        }
        if (m16 == 0) {
            int row = strip * 16 + quad * 4 + r;
            red[row * 4 + nh * 2 + 0] = s1;
            red[row * 4 + nh * 2 + 1] = s2;
        }
    }
    __syncthreads();

#pragma unroll
    for (int r = 0; r < 4; ++r) {
        int row = strip * 16 + quad * 4 + r;
        int node = n0 + (row & 63);
        if (node >= N_NODES) continue;
        int batch = row >> 6;
        float s1 = red[row * 4 + 0] + red[row * 4 + 2];
        float s2 = red[row * 4 + 1] + red[row * 4 + 3];
        float mean = s1 * (1.f / 256.f);
        float var  = s2 * (1.f / 256.f) - mean * mean;
        float rstd = rsqrtf(fmaxf(var, 0.f) + 1e-5f);
        float* xb = xs + (size_t)batch * PER_X + (size_t)node * NDIM;
        bf16_t* xhb = x16 + (size_t)batch * PER_X + (size_t)node * NDIM;
#pragma unroll
        for (int nt = 0; nt < 8; ++nt) {
            int c = nh * 128 + nt * 16 + m16;
            float ln = (v[r][nt] - mean) * rstd * g8[nt] + bl8[nt];
            float nv = xb[c] + ln;
            xb[c] = nv;
            xhb[c] = (bf16_t)nv;
        }
    }
}

extern "C" void kernel_launch(void* const* d_in, const int* in_sizes, int n_in,
                              void* d_out, int out_size, void* d_ws, size_t ws_size,
                              hipStream_t stream) {
    const float* nf   = (const float*)d_in[0];
    const float* ef   = (const float*)d_in[1];
    const float* We1  = (const float*)d_in[2];
    const float* be1  = (const float*)d_in[3];
    const float* We2  = (const float*)d_in[4];
    const float* be2  = (const float*)d_in[5];
    const float* ge   = (const float*)d_in[6];
    const float* ble  = (const float*)d_in[7];
    const float* Wn1  = (const float*)d_in[8];
    const float* bn1  = (const float*)d_in[9];
    const float* Wn2  = (const float*)d_in[10];
    const float* bn2  = (const float*)d_in[11];
    const float* gn   = (const float*)d_in[12];
    const float* bln  = (const float*)d_in[13];
    const int* eidx   = (const int*)d_in[14];

    float* xs = (float*)d_out;   // fp32 x-state accumulates in-place in d_out

    char* p = (char*)d_ws;
    bf16_t* es  = (bf16_t*)p; p += (size_t)2 * N_EDGES * EDIM * 2;
    bf16_t* x16 = (bf16_t*)p; p += (size_t)2 * N_NODES * NDIM * 2;
    bf16_t* w1ep = (bf16_t*)p; p += (size_t)NLAYERS * 576 * 512 * 2;
    bf16_t* w2ep = (bf16_t*)p; p += (size_t)NLAYERS * 512 * 64 * 2;
    bf16_t* w1np = (bf16_t*)p; p += (size_t)NLAYERS * 320 * 512 * 2;
    bf16_t* w2np = (bf16_t*)p; p += (size_t)NLAYERS * 512 * 256 * 2;
    int* deg = (int*)p; p += (size_t)40964 * 4;
    int* off = (int*)p; p += (size_t)40964 * 4;
    int* cur = (int*)p; p += (size_t)40964 * 4;
    int* csr = (int*)p; p += (size_t)N_EDGES * 4;

    repack_w<<<2304, 256, 0, stream>>>(We1, w1ep, 576, 512, 576, 1);
    repack_w<<<256,  256, 0, stream>>>(We2, w2ep, 512, 64,  64,  0);
    repack_w<<<1280, 256, 0, stream>>>(Wn1, w1np, 320, 512, 320, 0);
    repack_w<<<1024, 256, 0, stream>>>(Wn2, w2np, 512, 256, 256, 0);

    hipMemcpyAsync(xs, nf, (size_t)out_size * 4, hipMemcpyDeviceToDevice, stream);
    f32_to_bf16<<<2048, 256, 0, stream>>>(nf, x16, 2 * N_NODES * NDIM / 8);
    init_e2<<<2048, 256, 0, stream>>>(ef, es, N_EDGES * EDIM / 8);

    // one-time CSR over dst
    zero_f32<<<64, 256, 0, stream>>>((float*)deg, 40964 / 4);
    hist_k<<<N_EDGES / 256, 256, 0, stream>>>(eidx, deg);
    scan_k<<<1, 1024, 0, stream>>>(deg, off, cur);
    fill_k<<<N_EDGES / 256, 256, 0, stream>>>(eidx, cur, csr);

    for (int l = 0; l < NLAYERS; ++l) {
        edge_kernel<<<dim3(N_EDGES / 64), 1024, 0, stream>>>(
            x16, es, eidx,
            w1ep + (size_t)l * 576 * 512, be1 + l * 512,
            w2ep + (size_t)l * 512 * 64,  be2 + l * 64,
            ge + l * 64, ble + l * 64);
        node_kernel<<<dim3((N_NODES + 63) / 64), 1024, 0, stream>>>(
            xs, x16, es, off, csr,
            w1np + (size_t)l * 320 * 512, bn1 + l * 512,
            w2np + (size_t)l * 512 * 256, bn2 + l * 256,
            gn + l * 256, bln + l * 256);
    }
}